// Round 1
// baseline (1569.673 us; speedup 1.0000x reference)
//
#include <hip/hip_runtime.h>

// Problem constants (from reference)
#define E_DIM   2048
#define NHEADS  16
#define NBATCH  4
#define SLEN    2048
#define TLEN    2048
#define DHEAD   128
#define MROWS   (NBATCH * SLEN)   // 8192 rows for all projection GEMMs

typedef __bf16  bf16x8  __attribute__((ext_vector_type(8)));
typedef float   floatx4 __attribute__((ext_vector_type(4)));
typedef unsigned short ushort8_v __attribute__((ext_vector_type(8)));
typedef unsigned short ushort4_v __attribute__((ext_vector_type(4)));

// fp32 -> bf16 round-to-nearest-even
__device__ __forceinline__ unsigned short f2bf(float f) {
    unsigned int u = __builtin_bit_cast(unsigned int, f);
    u = (u + 0x7fffu + ((u >> 16) & 1u)) >> 16;
    return (unsigned short)u;
}

// ---------------------------------------------------------------------------
// GEMM: C[M,Nd] = A[M,K] * B[Nd,K]^T + bias[Nd]
// A: fp32 (A_IS_BF16=false) or bf16-as-ushort (true). B: fp32 weights.
// Out: bf16 (OUT_BF16=true) or fp32. 128x128 tile, BK=32, 4 waves (64x64 each).
// ---------------------------------------------------------------------------
#define BK  32
#define LDA 40   // LDS row stride in elements (32 + 8 pad: 80B rows, 16B aligned, 2-way banks)

template<bool A_IS_BF16, bool OUT_BF16>
__global__ __launch_bounds__(256, 2)
void gemm_bt(const void* __restrict__ Av, const float* __restrict__ B,
             const float* __restrict__ bias, void* __restrict__ Cv,
             int M, int Nd, int K)
{
    __shared__ unsigned short As[128 * LDA];
    __shared__ unsigned short Bs[128 * LDA];

    const int tid  = threadIdx.x;
    const int bm   = blockIdx.x * 128;
    const int bn   = blockIdx.y * 128;
    const int wave = tid >> 6, lane = tid & 63;
    const int wm   = (wave >> 1) * 64, wn = (wave & 1) * 64;
    const int lrow = lane & 15, quad = lane >> 4;

    floatx4 acc[4][4] = {};

    for (int k0 = 0; k0 < K; k0 += BK) {
        // ---- stage B (always fp32 weights, row-major [Nd,K]) ----
        {
            const int f = tid & 7, r0 = tid >> 3;   // f: float4 within 32-wide k window
            #pragma unroll
            for (int i = 0; i < 4; ++i) {
                const int row = r0 + 32 * i;
                const float4 v = *(const float4*)(B + (size_t)(bn + row) * K + k0 + f * 4);
                ushort4 w; w.x = f2bf(v.x); w.y = f2bf(v.y); w.z = f2bf(v.z); w.w = f2bf(v.w);
                *(ushort4*)&Bs[row * LDA + f * 4] = w;
            }
        }
        // ---- stage A ----
        if constexpr (!A_IS_BF16) {
            const float* A = (const float*)Av;
            const int f = tid & 7, r0 = tid >> 3;
            #pragma unroll
            for (int i = 0; i < 4; ++i) {
                const int row = r0 + 32 * i;
                const float4 v = *(const float4*)(A + (size_t)(bm + row) * K + k0 + f * 4);
                ushort4 w; w.x = f2bf(v.x); w.y = f2bf(v.y); w.z = f2bf(v.z); w.w = f2bf(v.w);
                *(ushort4*)&As[row * LDA + f * 4] = w;
            }
        } else {
            const unsigned short* A = (const unsigned short*)Av;
            const int f = tid & 3, r0 = tid >> 2;   // 4 chunks of 8 bf16 per 32-wide row
            #pragma unroll
            for (int i = 0; i < 2; ++i) {
                const int row = r0 + 64 * i;
                const unsigned short* src = A + (size_t)(bm + row) * K + k0 + f * 8;
                const ushort4_v v0 = *(const ushort4_v*)(src);
                const ushort4_v v1 = *(const ushort4_v*)(src + 4);
                *(ushort4_v*)&As[row * LDA + f * 8]     = v0;   // 8B writes (80B rows not 16B-mult)
                *(ushort4_v*)&As[row * LDA + f * 8 + 4] = v1;
            }
        }
        __syncthreads();

        bf16x8 af[4], bfr[4];
        #pragma unroll
        for (int mi = 0; mi < 4; ++mi)
            af[mi] = *(const bf16x8*)&As[(wm + mi * 16 + lrow) * LDA + quad * 8];
        #pragma unroll
        for (int ni = 0; ni < 4; ++ni)
            bfr[ni] = *(const bf16x8*)&Bs[(wn + ni * 16 + lrow) * LDA + quad * 8];
        #pragma unroll
        for (int mi = 0; mi < 4; ++mi)
            #pragma unroll
            for (int ni = 0; ni < 4; ++ni)
                acc[mi][ni] = __builtin_amdgcn_mfma_f32_16x16x32_bf16(af[mi], bfr[ni], acc[mi][ni], 0, 0, 0);
        __syncthreads();
    }

    // epilogue: C/D layout col=lane&15, row=quad*4+i  (m89-verified)
    #pragma unroll
    for (int ni = 0; ni < 4; ++ni) {
        const int col = bn + wn + ni * 16 + lrow;
        const float bv = bias[col];
        #pragma unroll
        for (int mi = 0; mi < 4; ++mi) {
            const int row = bm + wm + mi * 16 + quad * 4;
            #pragma unroll
            for (int i = 0; i < 4; ++i) {
                const float v = acc[mi][ni][i] + bv;
                if constexpr (OUT_BF16)
                    ((unsigned short*)Cv)[(size_t)(row + i) * Nd + col] = f2bf(v);
                else
                    ((float*)Cv)[(size_t)(row + i) * Nd + col] = v;
            }
        }
    }
}

// ---------------------------------------------------------------------------
// Mask tile summary: per 128x128 tile of mask[T,S]: 0=all-zero, 1=mixed, 2=all-ones
// ---------------------------------------------------------------------------
__global__ __launch_bounds__(256)
void mask_tiles(const int* __restrict__ mask, unsigned char* __restrict__ flags)
{
    __shared__ int s_and, s_or;
    const int tid = threadIdx.x;
    if (tid == 0) { s_and = 1; s_or = 0; }
    __syncthreads();
    const int tt = blockIdx.x >> 4;      // S/128 == 16 s-tiles
    const int ss = blockIdx.x & 15;
    int la = 1, lo = 0;
    #pragma unroll
    for (int it = 0; it < 16; ++it) {
        const int c = it * 256 + tid;            // 4096 int4 chunks per tile
        const int row = c >> 5, c4 = c & 31;
        const int4 v = *(const int4*)(mask + (size_t)(tt * 128 + row) * SLEN + ss * 128 + c4 * 4);
        const int nz = (v.x != 0) + (v.y != 0) + (v.z != 0) + (v.w != 0);
        la &= (nz == 4); lo |= (nz != 0);
    }
    if (!la) atomicAnd(&s_and, 0);
    if (lo)  atomicOr(&s_or, 1);
    __syncthreads();
    if (tid == 0) flags[blockIdx.x] = (unsigned char)(s_and ? 2 : (s_or ? 1 : 0));
}

// ---------------------------------------------------------------------------
// Transpose V: (N,T,H,D) bf16 -> Vt (N,H,D,T) bf16, 64x64 tiles through LDS
// ---------------------------------------------------------------------------
__global__ __launch_bounds__(256)
void transpose_v(const unsigned short* __restrict__ V, unsigned short* __restrict__ Vt)
{
    __shared__ unsigned short tl[64][80];   // stride 80 elems = 160B (16B aligned)
    const int tid = threadIdx.x;
    const int t0 = blockIdx.x * 64, d0 = blockIdx.y * 64;
    const int nh = blockIdx.z, n = nh >> 4, h = nh & 15;
    #pragma unroll
    for (int it = 0; it < 2; ++it) {
        const int c = it * 256 + tid;
        const int row = c >> 3, c8 = c & 7;
        *(ushort8_v*)&tl[row][c8 * 8] =
            *(const ushort8_v*)(V + ((size_t)(n * TLEN + t0 + row) * NHEADS + h) * DHEAD + d0 + c8 * 8);
    }
    __syncthreads();
    #pragma unroll
    for (int it = 0; it < 2; ++it) {
        const int c = it * 256 + tid;
        const int drow = c >> 3, t8 = c & 7;
        ushort8_v v;
        #pragma unroll
        for (int j = 0; j < 8; ++j) v[j] = tl[t8 * 8 + j][drow];
        *(ushort8_v*)(Vt + ((size_t)nh * DHEAD + d0 + drow) * TLEN + t0 + t8 * 8) = v;
    }
}

// ---------------------------------------------------------------------------
// Flash attention. Q (N,S,H,D) bf16, K (N,T,H,D) bf16, Vt (N,H,D,T) bf16.
// Grid: (S/128, H, N). 4 waves/block, each wave owns 32 query rows.
// Softmax over keys t; scale 1/sqrt(D) folded with log2(e) for exp2.
// ---------------------------------------------------------------------------
#define BT  128
#define LDK 136   // 128 + 8 pad: 272B rows (16B aligned)
#define LDP 136

__global__ __launch_bounds__(256, 1)
void flash_attn(const unsigned short* __restrict__ Q,
                const unsigned short* __restrict__ Kb,
                const unsigned short* __restrict__ Vt,
                const int* __restrict__ mask,
                const unsigned char* __restrict__ tflags,
                unsigned short* __restrict__ O)
{
    __shared__ unsigned short Ks[128 * LDK];
    __shared__ unsigned short Vs[128 * LDK];
    __shared__ unsigned short Ps[4][32 * LDP];

    const int tid  = threadIdx.x;
    const int s0   = blockIdx.x * 128;
    const int h    = blockIdx.y, n = blockIdx.z;
    const int wave = tid >> 6, lane = tid & 63;
    const int lrow = lane & 15, quad = lane >> 4;
    const int qbase = s0 + wave * 32;

    // Q fragments in registers (A-layout: m=lane&15, k=quad*8+j), rows qbase+mi*16+lrow
    bf16x8 aq[2][4];
    #pragma unroll
    for (int mi = 0; mi < 2; ++mi)
        #pragma unroll
        for (int kk = 0; kk < 4; ++kk)
            aq[mi][kk] = *(const bf16x8*)(Q + ((size_t)(n * SLEN + qbase + mi * 16 + lrow) * NHEADS + h) * DHEAD
                                            + kk * 32 + quad * 8);

    float m_r[2][4], l_r[2][4];
    floatx4 occ[2][8] = {};
    #pragma unroll
    for (int mi = 0; mi < 2; ++mi)
        #pragma unroll
        for (int i = 0; i < 4; ++i) { m_r[mi][i] = -INFINITY; l_r[mi][i] = 0.f; }

    const float sc = 0.08838834764831845f * 1.4426950408889634f; // 1/sqrt(128) * log2(e)

    for (int t0 = 0; t0 < TLEN; t0 += BT) {
        const int flag = tflags[(t0 >> 7) * (SLEN >> 7) + (s0 >> 7)];
        if (flag == 0) continue;   // fully-masked tile: contributes nothing (uniform -> no barrier hazard)

        // stage K tile (rows t, cols d) and V tile (rows d, cols t) into LDS
        #pragma unroll
        for (int it = 0; it < 8; ++it) {
            const int c = it * 256 + tid;
            const int row = c >> 4, c16 = c & 15;
            *(ushort8_v*)&Ks[row * LDK + c16 * 8] =
                *(const ushort8_v*)(Kb + ((size_t)(n * TLEN + t0 + row) * NHEADS + h) * DHEAD + c16 * 8);
            *(ushort8_v*)&Vs[row * LDK + c16 * 8] =
                *(const ushort8_v*)(Vt + ((size_t)(n * NHEADS + h) * DHEAD + row) * TLEN + t0 + c16 * 8);
        }
        __syncthreads();

        // S = Q * K^T  (rows=queries, cols=keys)
        floatx4 sacc[2][8] = {};
        #pragma unroll
        for (int kk = 0; kk < 4; ++kk)
            #pragma unroll
            for (int ni = 0; ni < 8; ++ni) {
                const bf16x8 bk = *(const bf16x8*)&Ks[(ni * 16 + lrow) * LDK + kk * 32 + quad * 8];
                sacc[0][ni] = __builtin_amdgcn_mfma_f32_16x16x32_bf16(aq[0][kk], bk, sacc[0][ni], 0, 0, 0);
                sacc[1][ni] = __builtin_amdgcn_mfma_f32_16x16x32_bf16(aq[1][kk], bk, sacc[1][ni], 0, 0, 0);
            }

        // scale (base-2 domain) + optional mask
        #pragma unroll
        for (int mi = 0; mi < 2; ++mi)
            #pragma unroll
            for (int ni = 0; ni < 8; ++ni)
                #pragma unroll
                for (int i = 0; i < 4; ++i) sacc[mi][ni][i] *= sc;

        if (flag == 1) {
            #pragma unroll
            for (int mi = 0; mi < 2; ++mi)
                #pragma unroll
                for (int ni = 0; ni < 8; ++ni)
                    #pragma unroll
                    for (int i = 0; i < 4; ++i) {
                        const int t = t0 + ni * 16 + lrow;
                        const int s = s0 + wave * 32 + mi * 16 + quad * 4 + i;
                        if (mask[(size_t)t * SLEN + s] == 0) sacc[mi][ni][i] = -INFINITY;
                    }
        }

        // row max over keys: local over ni, then across the 16 lanes of the quad
        float mt[2][4];
        #pragma unroll
        for (int mi = 0; mi < 2; ++mi)
            #pragma unroll
            for (int i = 0; i < 4; ++i) {
                float v = sacc[mi][0][i];
                #pragma unroll
                for (int ni = 1; ni < 8; ++ni) v = fmaxf(v, sacc[mi][ni][i]);
                mt[mi][i] = v;
            }
        #pragma unroll
        for (int off = 1; off < 16; off <<= 1)
            #pragma unroll
            for (int mi = 0; mi < 2; ++mi)
                #pragma unroll
                for (int i = 0; i < 4; ++i)
                    mt[mi][i] = fmaxf(mt[mi][i], __shfl_xor(mt[mi][i], off));

        float alpha[2][4], psum[2][4];
        #pragma unroll
        for (int mi = 0; mi < 2; ++mi)
            #pragma unroll
            for (int i = 0; i < 4; ++i) {
                const float mnew = fmaxf(m_r[mi][i], mt[mi][i]);
                alpha[mi][i] = (mnew == -INFINITY) ? 0.f : exp2f(m_r[mi][i] - mnew);
                m_r[mi][i] = mnew;
                psum[mi][i] = 0.f;
            }

        // P = exp2(s' - m), write to LDS in A-layout rows, accumulate row sums
        #pragma unroll
        for (int mi = 0; mi < 2; ++mi)
            #pragma unroll
            for (int ni = 0; ni < 8; ++ni)
                #pragma unroll
                for (int i = 0; i < 4; ++i) {
                    const float p = (m_r[mi][i] == -INFINITY) ? 0.f : exp2f(sacc[mi][ni][i] - m_r[mi][i]);
                    psum[mi][i] += p;
                    Ps[wave][(mi * 16 + quad * 4 + i) * LDP + ni * 16 + lrow] = f2bf(p);
                }
        #pragma unroll
        for (int off = 1; off < 16; off <<= 1)
            #pragma unroll
            for (int mi = 0; mi < 2; ++mi)
                #pragma unroll
                for (int i = 0; i < 4; ++i)
                    psum[mi][i] += __shfl_xor(psum[mi][i], off);

        #pragma unroll
        for (int mi = 0; mi < 2; ++mi)
            #pragma unroll
            for (int i = 0; i < 4; ++i)
                l_r[mi][i] = l_r[mi][i] * alpha[mi][i] + psum[mi][i];
        #pragma unroll
        for (int mi = 0; mi < 2; ++mi)
            #pragma unroll
            for (int nd = 0; nd < 8; ++nd)
                #pragma unroll
                for (int i = 0; i < 4; ++i)
                    occ[mi][nd][i] *= alpha[mi][i];

        // O += P * V   (A = P from LDS, B = V^T tile: contiguous in t)
        #pragma unroll
        for (int kk = 0; kk < 4; ++kk) {
            const bf16x8 ap0 = *(const bf16x8*)&Ps[wave][(lrow) * LDP + kk * 32 + quad * 8];
            const bf16x8 ap1 = *(const bf16x8*)&Ps[wave][(16 + lrow) * LDP + kk * 32 + quad * 8];
            #pragma unroll
            for (int nd = 0; nd < 8; ++nd) {
                const bf16x8 bv = *(const bf16x8*)&Vs[(nd * 16 + lrow) * LDK + kk * 32 + quad * 8];
                occ[0][nd] = __builtin_amdgcn_mfma_f32_16x16x32_bf16(ap0, bv, occ[0][nd], 0, 0, 0);
                occ[1][nd] = __builtin_amdgcn_mfma_f32_16x16x32_bf16(ap1, bv, occ[1][nd], 0, 0, 0);
            }
        }
        __syncthreads();
    }

    // normalize and store O (N,S,H,D) bf16
    float rl[2][4];
    #pragma unroll
    for (int mi = 0; mi < 2; ++mi)
        #pragma unroll
        for (int i = 0; i < 4; ++i)
            rl[mi][i] = (l_r[mi][i] > 0.f) ? 1.0f / l_r[mi][i] : 0.f;
    #pragma unroll
    for (int mi = 0; mi < 2; ++mi)
        #pragma unroll
        for (int nd = 0; nd < 8; ++nd)
            #pragma unroll
            for (int i = 0; i < 4; ++i) {
                const int srow = s0 + wave * 32 + mi * 16 + quad * 4 + i;
                O[((size_t)(n * SLEN + srow) * NHEADS + h) * DHEAD + nd * 16 + lrow] =
                    f2bf(occ[mi][nd][i] * rl[mi][i]);
            }
}

// ---------------------------------------------------------------------------
extern "C" void kernel_launch(void* const* d_in, const int* in_sizes, int n_in,
                              void* d_out, int out_size, void* d_ws, size_t ws_size,
                              hipStream_t stream)
{
    const float* query = (const float*)d_in[0];
    const float* key   = (const float*)d_in[1];
    const float* value = (const float*)d_in[2];
    const int*   mask  = (const int*)d_in[3];
    const float* Wq = (const float*)d_in[4];  const float* bq = (const float*)d_in[5];
    const float* Wk = (const float*)d_in[6];  const float* bk = (const float*)d_in[7];
    const float* Wv = (const float*)d_in[8];  const float* bv = (const float*)d_in[9];
    const float* Wp = (const float*)d_in[10]; const float* bp = (const float*)d_in[11];
    float* out = (float*)d_out;

    char* ws = (char*)d_ws;
    const size_t SZ = (size_t)MROWS * E_DIM * 2;           // 32 MB per bf16 tensor
    unsigned short* Qb  = (unsigned short*)(ws);
    unsigned short* Kbf = (unsigned short*)(ws + SZ);
    unsigned short* Vb  = (unsigned short*)(ws + 2 * SZ);
    unsigned short* Vtb = (unsigned short*)(ws + 3 * SZ);
    unsigned short* Ob  = Vb;                               // reuse V after transpose
    unsigned char*  flags = (unsigned char*)(ws + 4 * SZ); // needs ws >= 128MB + 256B

    const dim3 gg(MROWS / 128, E_DIM / 128);

    mask_tiles<<<256, 256, 0, stream>>>(mask, flags);
    gemm_bt<false, true><<<gg, 256, 0, stream>>>(query, Wq, bq, Qb,  MROWS, E_DIM, E_DIM);
    gemm_bt<false, true><<<gg, 256, 0, stream>>>(key,   Wk, bk, Kbf, MROWS, E_DIM, E_DIM);
    gemm_bt<false, true><<<gg, 256, 0, stream>>>(value, Wv, bv, Vb,  MROWS, E_DIM, E_DIM);
    transpose_v<<<dim3(TLEN / 64, DHEAD / 64, NBATCH * NHEADS), 256, 0, stream>>>(Vb, Vtb);
    flash_attn<<<dim3(SLEN / 128, NHEADS, NBATCH), 256, 0, stream>>>(Qb, Kbf, Vtb, mask, flags, Ob);
    gemm_bt<true, false><<<gg, 256, 0, stream>>>(Ob, Wp, bp, out, MROWS, E_DIM, E_DIM);
}

// Round 3
// 1018.453 us; speedup vs baseline: 1.5412x; 1.5412x over previous
//
#include <hip/hip_runtime.h>

#define E_DIM   2048
#define NHEADS  16
#define NBATCH  4
#define SLEN    2048
#define TLEN    2048
#define DHEAD   128
#define MROWS   (NBATCH * SLEN)   // 8192

typedef __bf16  bf16x8  __attribute__((ext_vector_type(8)));
typedef float   floatx4 __attribute__((ext_vector_type(4)));
typedef unsigned short ushort8_v __attribute__((ext_vector_type(8)));

__device__ __forceinline__ unsigned short f2bf(float f) {
    unsigned int u = __builtin_bit_cast(unsigned int, f);
    u = (u + 0x7fffu + ((u >> 16) & 1u)) >> 16;
    return (unsigned short)u;
}
// pack two fp32 -> bf16x2 in one uint (lo = a, hi = b)
__device__ __forceinline__ unsigned int f2bf2(float a, float b) {
    return (unsigned int)f2bf(a) | ((unsigned int)f2bf(b) << 16);
}

// async global->LDS, 16 B per lane: LDS dest = wave-uniform base + lane*16
__device__ __forceinline__ void gload16(const unsigned short* g, unsigned short* l) {
    __builtin_amdgcn_global_load_lds(
        (const __attribute__((address_space(1))) unsigned int*)(const void*)g,
        (__attribute__((address_space(3))) unsigned int*)(void*)l, 16, 0, 0);
}

// ---------------------------------------------------------------------------
// fp32 -> bf16 conversion kernels
// ---------------------------------------------------------------------------
__global__ __launch_bounds__(256)
void conv_qkv(const float* __restrict__ q, const float* __restrict__ k,
              const float* __restrict__ v, unsigned short* __restrict__ dst)
{
    const float* src = (blockIdx.y == 0) ? q : ((blockIdx.y == 1) ? k : v);
    const size_t base = (size_t)blockIdx.y * ((size_t)MROWS * E_DIM);
    const size_t i = ((size_t)blockIdx.x * 256 + threadIdx.x) * 8;
    const float4 a = *(const float4*)(src + i);
    const float4 b = *(const float4*)(src + i + 4);
    ushort8_v o;
    o[0]=f2bf(a.x); o[1]=f2bf(a.y); o[2]=f2bf(a.z); o[3]=f2bf(a.w);
    o[4]=f2bf(b.x); o[5]=f2bf(b.y); o[6]=f2bf(b.z); o[7]=f2bf(b.w);
    *(ushort8_v*)(dst + base + i) = o;
}

__global__ __launch_bounds__(256)
void conv_w(const float* __restrict__ w0, const float* __restrict__ w1,
            const float* __restrict__ w2, const float* __restrict__ w3,
            unsigned short* __restrict__ dst)
{
    const float* src = (blockIdx.y == 0) ? w0 : ((blockIdx.y == 1) ? w1 :
                       ((blockIdx.y == 2) ? w2 : w3));
    const size_t base = (size_t)blockIdx.y * ((size_t)E_DIM * E_DIM);
    const size_t i = ((size_t)blockIdx.x * 256 + threadIdx.x) * 8;
    const float4 a = *(const float4*)(src + i);
    const float4 b = *(const float4*)(src + i + 4);
    ushort8_v o;
    o[0]=f2bf(a.x); o[1]=f2bf(a.y); o[2]=f2bf(a.z); o[3]=f2bf(a.w);
    o[4]=f2bf(b.x); o[5]=f2bf(b.y); o[6]=f2bf(b.z); o[7]=f2bf(b.w);
    *(ushort8_v*)(dst + base + i) = o;
}

// ---------------------------------------------------------------------------
// GEMM: C[M,Nd] = (A[M,K] * B[Nd,K]^T + bias) * scale. A,B bf16. m97 pattern:
// global_load_lds width=16, unpadded [128][32] LDS, XOR chunk swizzle
// (phys = log ^ ((row>>1)&3)) -> 2-way banks (free) on ds_read_b128.
// EPI: 0 = fp32 std layout, 1 = bf16 std layout, 2 = bf16 direct-V^T layout.
// ---------------------------------------------------------------------------
template<int EPI>
__global__ __launch_bounds__(256, 2)
void gemm_bt(const unsigned short* __restrict__ A, const unsigned short* __restrict__ B,
             const float* __restrict__ bias, void* __restrict__ Cv,
             int M, int Nd, int K, float scale)
{
    __shared__ unsigned short As[128 * 32];
    __shared__ unsigned short Bs[128 * 32];

    const int tid  = threadIdx.x;
    const int bm   = blockIdx.x * 128;
    const int bn   = blockIdx.y * 128;
    const int wave = tid >> 6, lane = tid & 63;
    const int wm   = (wave >> 1) * 64, wn = (wave & 1) * 64;
    const int lrow = lane & 15, quad = lane >> 4;

    // staging lane mapping: row = lane/4, physical chunk = lane%4
    const int srow = lane >> 2, schk = lane & 3;
    const int slog = schk ^ ((srow >> 1) & 3);           // logical chunk in global
    const unsigned short* ag = A + (size_t)(bm + wave * 32 + srow) * K + slog * 8;
    const unsigned short* bg = B + (size_t)(bn + wave * 32 + srow) * K + slog * 8;
    unsigned short* lA0 = &As[(wave * 32) * 32];
    unsigned short* lA1 = &As[(wave * 32 + 16) * 32];
    unsigned short* lB0 = &Bs[(wave * 32) * 32];
    unsigned short* lB1 = &Bs[(wave * 32 + 16) * 32];

    const int aswz = (quad ^ ((lrow >> 1) & 3)) * 8;     // read-side physical chunk

    floatx4 acc[4][4] = {};

    for (int k0 = 0; k0 < K; k0 += 32) {
        gload16(ag + k0,                  lA0);
        gload16(ag + (size_t)16 * K + k0, lA1);
        gload16(bg + k0,                  lB0);
        gload16(bg + (size_t)16 * K + k0, lB1);
        __syncthreads();   // drains vmcnt -> staged data visible

        bf16x8 af[4], bfr[4];
        #pragma unroll
        for (int mi = 0; mi < 4; ++mi)
            af[mi] = *(const bf16x8*)&As[(wm + mi * 16 + lrow) * 32 + aswz];
        #pragma unroll
        for (int ni = 0; ni < 4; ++ni)
            bfr[ni] = *(const bf16x8*)&Bs[(wn + ni * 16 + lrow) * 32 + aswz];
        #pragma unroll
        for (int mi = 0; mi < 4; ++mi)
            #pragma unroll
            for (int ni = 0; ni < 4; ++ni)
                acc[mi][ni] = __builtin_amdgcn_mfma_f32_16x16x32_bf16(af[mi], bfr[ni], acc[mi][ni], 0, 0, 0);
        __syncthreads();
    }

    // epilogue: C/D layout col=lane&15, row=quad*4+i
    #pragma unroll
    for (int ni = 0; ni < 4; ++ni) {
        const int col = bn + wn + ni * 16 + lrow;
        const float bv = bias[col];
        #pragma unroll
        for (int mi = 0; mi < 4; ++mi) {
            const int row = bm + wm + mi * 16 + quad * 4;
            if constexpr (EPI == 2) {
                // write V^T directly: (N,T,E)[row=(n,t), col=(h,d)] -> Vt(N,H,D,T)
                const int n = row >> 11, t = row & 2047;
                const int hh = col >> 7, dd = col & 127;
                unsigned short* dst = (unsigned short*)Cv +
                    (((size_t)(n * 16 + hh) * 128 + dd) * 2048 + t);
                ushort4 w;
                w.x = f2bf((acc[mi][ni][0] + bv) * scale);
                w.y = f2bf((acc[mi][ni][1] + bv) * scale);
                w.z = f2bf((acc[mi][ni][2] + bv) * scale);
                w.w = f2bf((acc[mi][ni][3] + bv) * scale);
                *(ushort4*)dst = w;   // 4 consecutive t, 8B aligned
            } else {
                #pragma unroll
                for (int i = 0; i < 4; ++i) {
                    const float v = (acc[mi][ni][i] + bv) * scale;
                    if constexpr (EPI == 1)
                        ((unsigned short*)Cv)[(size_t)(row + i) * Nd + col] = f2bf(v);
                    else
                        ((float*)Cv)[(size_t)(row + i) * Nd + col] = v;
                }
            }
        }
    }
}

// ---------------------------------------------------------------------------
// Mask tile summary: per 128x128 tile of mask[T,S]: 0=all-zero, 1=mixed, 2=all-ones
// ---------------------------------------------------------------------------
__global__ __launch_bounds__(256)
void mask_tiles(const int* __restrict__ mask, unsigned char* __restrict__ flags)
{
    __shared__ int s_and, s_or;
    const int tid = threadIdx.x;
    if (tid == 0) { s_and = 1; s_or = 0; }
    __syncthreads();
    const int tt = blockIdx.x >> 4;
    const int ss = blockIdx.x & 15;
    int la = 1, lo = 0;
    #pragma unroll
    for (int it = 0; it < 16; ++it) {
        const int c = it * 256 + tid;
        const int row = c >> 5, c4 = c & 31;
        const int4 v = *(const int4*)(mask + (size_t)(tt * 128 + row) * SLEN + ss * 128 + c4 * 4);
        const int nz = (v.x != 0) + (v.y != 0) + (v.z != 0) + (v.w != 0);
        la &= (nz == 4); lo |= (nz != 0);
    }
    if (!la) atomicAnd(&s_and, 0);
    if (lo)  atomicOr(&s_or, 1);
    __syncthreads();
    if (tid == 0) flags[blockIdx.x] = (unsigned char)(s_and ? 2 : (s_or ? 1 : 0));
}

// ---------------------------------------------------------------------------
// Flash attention, transposed scores. Q pre-scaled by (1/sqrt(d))*log2(e).
// QK^T computed as S^T = K·Q^T -> C-layout lane holds [t=ti*16+quad*4+i][s=si*16+lrow]:
// i-register = consecutive t -> packed b64 P writes; softmax reduce = 2 shuffles.
// P staged per-wave in 32-wide chunks fused with PV (Ps = 10 KB). 79.9 KB LDS
// -> 2 blocks/CU.
// ---------------------------------------------------------------------------
#define LDK  136   // K/V tile row stride (272 B, 16B-aligned, conflict-free)
#define LDP2 40    // P chunk row stride (80 B)

__global__ __launch_bounds__(256, 2)
void flash_attn(const unsigned short* __restrict__ Q,
                const unsigned short* __restrict__ Kb,
                const unsigned short* __restrict__ Vt,
                const int* __restrict__ mask,
                const unsigned char* __restrict__ tflags,
                unsigned short* __restrict__ O)
{
    __shared__ unsigned short Ks[128 * LDK];
    __shared__ unsigned short Vs[128 * LDK];
    __shared__ unsigned short Ps[4][32 * LDP2];

    const int tid  = threadIdx.x;
    const int s0   = blockIdx.x * 128;
    const int h    = blockIdx.y, n = blockIdx.z;
    const int wave = tid >> 6, lane = tid & 63;
    const int lrow = lane & 15, quad = lane >> 4;
    const int qbase = s0 + wave * 32;

    // Q fragments (B-operand layout == A layout: n=lane&15, k=quad*8+j)
    bf16x8 aq[2][4];
    #pragma unroll
    for (int si = 0; si < 2; ++si)
        #pragma unroll
        for (int kk = 0; kk < 4; ++kk)
            aq[si][kk] = *(const bf16x8*)(Q + ((size_t)(n * SLEN + qbase + si * 16 + lrow) * NHEADS + h) * DHEAD
                                            + kk * 32 + quad * 8);

    float m_r[2] = { -INFINITY, -INFINITY };
    float l_r[2] = { 0.f, 0.f };
    floatx4 occ[2][8] = {};

    for (int t0 = 0; t0 < TLEN; t0 += 128) {
        const int flag = tflags[(t0 >> 7) * (SLEN >> 7) + (s0 >> 7)];
        if (flag == 0) continue;   // uniform per block

        // stage K tile [t][d] and V^T tile [d][t]
        #pragma unroll
        for (int it = 0; it < 8; ++it) {
            const int c = it * 256 + tid;
            const int row = c >> 4, c16 = c & 15;
            *(ushort8_v*)&Ks[row * LDK + c16 * 8] =
                *(const ushort8_v*)(Kb + ((size_t)(n * TLEN + t0 + row) * NHEADS + h) * DHEAD + c16 * 8);
            *(ushort8_v*)&Vs[row * LDK + c16 * 8] =
                *(const ushort8_v*)(Vt + ((size_t)(n * NHEADS + h) * DHEAD + row) * TLEN + t0 + c16 * 8);
        }
        __syncthreads();

        // S^T = K * Q^T : D[m=t][n=s]
        floatx4 sacc[8][2] = {};
        #pragma unroll
        for (int kk = 0; kk < 4; ++kk)
            #pragma unroll
            for (int ti = 0; ti < 8; ++ti) {
                const bf16x8 ak = *(const bf16x8*)&Ks[(ti * 16 + lrow) * LDK + kk * 32 + quad * 8];
                sacc[ti][0] = __builtin_amdgcn_mfma_f32_16x16x32_bf16(ak, aq[0][kk], sacc[ti][0], 0, 0, 0);
                sacc[ti][1] = __builtin_amdgcn_mfma_f32_16x16x32_bf16(ak, aq[1][kk], sacc[ti][1], 0, 0, 0);
            }

        if (flag == 1) {
            #pragma unroll
            for (int ti = 0; ti < 8; ++ti)
                #pragma unroll
                for (int si = 0; si < 2; ++si)
                    #pragma unroll
                    for (int i = 0; i < 4; ++i) {
                        const int t = t0 + ti * 16 + quad * 4 + i;
                        const int s = s0 + wave * 32 + si * 16 + lrow;
                        if (mask[(size_t)t * SLEN + s] == 0) sacc[ti][si][i] = -INFINITY;
                    }
        }

        // row stats: in-lane over (ti,i), then across quads (xor 16, 32)
        float mt[2];
        #pragma unroll
        for (int si = 0; si < 2; ++si) {
            float v = sacc[0][si][0];
            #pragma unroll
            for (int ti = 0; ti < 8; ++ti)
                #pragma unroll
                for (int i = 0; i < 4; ++i) v = fmaxf(v, sacc[ti][si][i]);
            v = fmaxf(v, __shfl_xor(v, 16));
            v = fmaxf(v, __shfl_xor(v, 32));
            mt[si] = v;
        }

        float alpha[2];
        #pragma unroll
        for (int si = 0; si < 2; ++si) {
            const float mnew = fmaxf(m_r[si], mt[si]);
            alpha[si] = (mnew == -INFINITY) ? 0.f : exp2f(m_r[si] - mnew);
            m_r[si] = mnew;
        }

        // broadcast alpha to O-accumulator layout (s = si*16 + quad*4 + i)
        float ao[2][4];
        #pragma unroll
        for (int si = 0; si < 2; ++si)
            #pragma unroll
            for (int i = 0; i < 4; ++i)
                ao[si][i] = __shfl(alpha[si], quad * 4 + i);
        #pragma unroll
        for (int si = 0; si < 2; ++si)
            #pragma unroll
            for (int nd = 0; nd < 8; ++nd)
                #pragma unroll
                for (int i = 0; i < 4; ++i)
                    occ[si][nd][i] *= ao[si][i];

        // fused exp + P-chunk staging + PV (per-wave Ps: same-wave DS ordering, no barrier)
        float psum[2] = { 0.f, 0.f };
        #pragma unroll
        for (int kk = 0; kk < 4; ++kk) {
            #pragma unroll
            for (int si = 0; si < 2; ++si)
                #pragma unroll
                for (int half = 0; half < 2; ++half) {
                    const int ti = kk * 2 + half;
                    float p[4];
                    #pragma unroll
                    for (int i = 0; i < 4; ++i) {
                        const float e = exp2f(sacc[ti][si][i] - m_r[si]);
                        p[i] = (m_r[si] == -INFINITY) ? 0.f : e;
                    }
                    psum[si] += (p[0] + p[1]) + (p[2] + p[3]);
                    uint2 w;
                    w.x = f2bf2(p[0], p[1]);
                    w.y = f2bf2(p[2], p[3]);
                    *(uint2*)&Ps[wave][(si * 16 + lrow) * LDP2 + half * 16 + quad * 4] = w;
                }
            bf16x8 ap[2];
            #pragma unroll
            for (int si = 0; si < 2; ++si)
                ap[si] = *(const bf16x8*)&Ps[wave][(si * 16 + lrow) * LDP2 + quad * 8];
            #pragma unroll
            for (int nd = 0; nd < 8; ++nd) {
                const bf16x8 bv = *(const bf16x8*)&Vs[(nd * 16 + lrow) * LDK + kk * 32 + quad * 8];
                occ[0][nd] = __builtin_amdgcn_mfma_f32_16x16x32_bf16(ap[0], bv, occ[0][nd], 0, 0, 0);
                occ[1][nd] = __builtin_amdgcn_mfma_f32_16x16x32_bf16(ap[1], bv, occ[1][nd], 0, 0, 0);
            }
        }

        #pragma unroll
        for (int si = 0; si < 2; ++si) {
            psum[si] += __shfl_xor(psum[si], 16);
            psum[si] += __shfl_xor(psum[si], 32);
            l_r[si] = l_r[si] * alpha[si] + psum[si];
        }
        __syncthreads();
    }

    // normalize (broadcast 1/l to O layout) and store O (N,S,H,D) bf16
    float rl[2];
    #pragma unroll
    for (int si = 0; si < 2; ++si)
        rl[si] = (l_r[si] > 0.f) ? 1.0f / l_r[si] : 0.f;
    float rlo[2][4];
    #pragma unroll
    for (int si = 0; si < 2; ++si)
        #pragma unroll
        for (int i = 0; i < 4; ++i)
            rlo[si][i] = __shfl(rl[si], quad * 4 + i);

    #pragma unroll
    for (int si = 0; si < 2; ++si)
        #pragma unroll
        for (int nd = 0; nd < 8; ++nd)
            #pragma unroll
            for (int i = 0; i < 4; ++i) {
                const int srow = s0 + wave * 32 + si * 16 + quad * 4 + i;
                O[((size_t)(n * SLEN + srow) * NHEADS + h) * DHEAD + nd * 16 + lrow] =
                    f2bf(occ[si][nd][i] * rlo[si][i]);
            }
}

// ---------------------------------------------------------------------------
extern "C" void kernel_launch(void* const* d_in, const int* in_sizes, int n_in,
                              void* d_out, int out_size, void* d_ws, size_t ws_size,
                              hipStream_t stream)
{
    const float* query = (const float*)d_in[0];
    const float* key   = (const float*)d_in[1];
    const float* value = (const float*)d_in[2];
    const int*   mask  = (const int*)d_in[3];
    const float* Wq = (const float*)d_in[4];  const float* bq = (const float*)d_in[5];
    const float* Wk = (const float*)d_in[6];  const float* bk = (const float*)d_in[7];
    const float* Wv = (const float*)d_in[8];  const float* bv = (const float*)d_in[9];
    const float* Wp = (const float*)d_in[10]; const float* bp = (const float*)d_in[11];
    float* out = (float*)d_out;

    // ws layout (128 MB + 256 B): [Wb 32MB][A 32MB][B 32MB][C 32MB][flags]
    char* ws = (char*)d_ws;
    const size_t SLOT = 32ull * 1024 * 1024;
    unsigned short* Wb  = (unsigned short*)ws;              // 4 bf16 weights
    unsigned short* Abf = (unsigned short*)(ws + SLOT);     // q_bf -> later V^T
    unsigned short* Bbf = (unsigned short*)(ws + 2 * SLOT); // k_bf
    unsigned short* Cbf = (unsigned short*)(ws + 3 * SLOT); // v_bf -> later attn out
    unsigned char*  flags = (unsigned char*)(ws + 4 * SLOT);
    // Q/K projections parked in d_out (64 MB, dead before final GEMM writes it)
    unsigned short* Qb  = (unsigned short*)d_out;
    unsigned short* Kbb = (unsigned short*)((char*)d_out + SLOT);

    const size_t WSLOT = (size_t)E_DIM * E_DIM;
    const dim3 gg(MROWS / 128, E_DIM / 128);
    const float sc = 0.08838834764831845f * 1.4426950408889634f; // 1/sqrt(128)*log2(e)

    mask_tiles<<<256, 256, 0, stream>>>(mask, flags);
    conv_qkv<<<dim3(8192, 3), 256, 0, stream>>>(query, key, value, Abf);
    conv_w<<<dim3(2048, 4), 256, 0, stream>>>(Wq, Wk, Wv, Wp, Wb);

    gemm_bt<1><<<gg, 256, 0, stream>>>(Abf, Wb,             bq, Qb,  MROWS, E_DIM, E_DIM, sc);
    gemm_bt<1><<<gg, 256, 0, stream>>>(Bbf, Wb + WSLOT,     bk, Kbb, MROWS, E_DIM, E_DIM, 1.f);
    gemm_bt<2><<<gg, 256, 0, stream>>>(Cbf, Wb + 2 * WSLOT, bv, Abf, MROWS, E_DIM, E_DIM, 1.f);
    flash_attn<<<dim3(SLEN / 128, NHEADS, NBATCH), 256, 0, stream>>>(Qb, Kbb, Abf, mask, flags, Cbf);
    gemm_bt<0><<<gg, 256, 0, stream>>>(Cbf, Wb + 3 * WSLOT, bp, out, MROWS, E_DIM, E_DIM, 1.f);
}